// Round 1
// baseline (1207.852 us; speedup 1.0000x reference)
//
#include <hip/hip_runtime.h>
#include <math.h>

#define N_NODES 50000
#define N_EDGES 800000
#define F_IN    86
#define H_DIM   128
#define ED_DIM  16
#define C_CLS   18
#define G_GRAPHS 64
#define NEG_SLOPE 0.2f

__device__ __forceinline__ void atomicMaxFloat(float* addr, float val) {
    // works for mixed signs: positive floats compare as ints, negative floats
    // compare inverted as uints; init value must be -inf
    if (val >= 0.0f) atomicMax((int*)addr, __float_as_int(val));
    else             atomicMin((unsigned int*)addr, __float_as_uint(val));
}

// ve[d] = sum_h We[d*H+h] * ae[h]   (collapses e@ae to edge_attr@ve)
__global__ void compute_ve(const float* __restrict__ We1, const float* __restrict__ ae1,
                           const float* __restrict__ We2, const float* __restrict__ ae2,
                           float* __restrict__ ve1, float* __restrict__ ve2) {
    int t = threadIdx.x;
    if (t < ED_DIM) {
        float s = 0.f;
        for (int h = 0; h < H_DIM; ++h) s += We1[t * H_DIM + h] * ae1[h];
        ve1[t] = s;
    } else if (t < 2 * ED_DIM) {
        int j = t - ED_DIM;
        float s = 0.f;
        for (int h = 0; h < H_DIM; ++h) s += We2[j * H_DIM + h] * ae2[h];
        ve2[j] = s;
    }
}

__global__ void init_nodes(float* __restrict__ m, float* __restrict__ denom) {
    int i = blockIdx.x * blockDim.x + threadIdx.x;
    if (i < N_NODES) { m[i] = -INFINITY; denom[i] = 0.f; }
}

__global__ void init_pooled(float* __restrict__ pooled) {
    int i = blockIdx.x * blockDim.x + threadIdx.x;
    if (i < G_GRAPHS * H_DIM) pooled[i] = -INFINITY;
}

// h[n,:] = act(in[n,:]) @ W    where act = relu(x + bias) if bias != null else x
// 16 rows per block, 128 threads (one output column each)
template<int K>
__global__ void gemm_node(const float* __restrict__ in, const float* __restrict__ bias,
                          const float* __restrict__ W, float* __restrict__ h) {
    __shared__ float xs[16 * K];
    int t = threadIdx.x;
    int n0 = blockIdx.x * 16;
    for (int idx = t; idx < 16 * K; idx += 128) {
        int r = idx / K, k = idx % K;
        float v = in[(size_t)(n0 + r) * K + k];
        if (bias) v = fmaxf(v + bias[k], 0.f);
        xs[idx] = v;
    }
    __syncthreads();
    float acc[16];
#pragma unroll
    for (int r = 0; r < 16; ++r) acc[r] = 0.f;
#pragma unroll 2
    for (int k = 0; k < K; ++k) {
        float w = W[k * H_DIM + t];
#pragma unroll
        for (int r = 0; r < 16; ++r) acc[r] += xs[r * K + k] * w;
    }
#pragma unroll
    for (int r = 0; r < 16; ++r) h[(size_t)(n0 + r) * H_DIM + t] = acc[r];
}

// hs[n] = h[n,:].a_src ; hd[n] = h[n,:].a_dst  — one wave per node
__global__ void node_dots(const float* __restrict__ h,
                          const float* __restrict__ a_s, const float* __restrict__ a_d,
                          float* __restrict__ hs, float* __restrict__ hd) {
    int n = blockIdx.x;
    int t = threadIdx.x;  // 64
    float v0 = h[(size_t)n * H_DIM + t];
    float v1 = h[(size_t)n * H_DIM + t + 64];
    float ss = v0 * a_s[t] + v1 * a_s[t + 64];
    float sd = v0 * a_d[t] + v1 * a_d[t + 64];
    for (int o = 32; o > 0; o >>= 1) {
        ss += __shfl_down(ss, o);
        sd += __shfl_down(sd, o);
    }
    if (t == 0) { hs[n] = ss; hd[n] = sd; }
}

__global__ void edge_alpha(const int* __restrict__ src, const int* __restrict__ dst,
                           const float* __restrict__ ea, const float* __restrict__ ve,
                           const float* __restrict__ hs, const float* __restrict__ hd,
                           float* __restrict__ alpha) {
    int e = blockIdx.x * blockDim.x + threadIdx.x;
    if (e >= N_EDGES) return;
    const float4* p = (const float4*)(ea + (size_t)e * ED_DIM);
    float4 v0 = p[0], v1 = p[1], v2 = p[2], v3 = p[3];
    float s = v0.x * ve[0] + v0.y * ve[1] + v0.z * ve[2] + v0.w * ve[3]
            + v1.x * ve[4] + v1.y * ve[5] + v1.z * ve[6] + v1.w * ve[7]
            + v2.x * ve[8] + v2.y * ve[9] + v2.z * ve[10] + v2.w * ve[11]
            + v3.x * ve[12] + v3.y * ve[13] + v3.z * ve[14] + v3.w * ve[15];
    s += hs[src[e]] + hd[dst[e]];
    alpha[e] = (s > 0.f) ? s : NEG_SLOPE * s;
}

__global__ void seg_max_k(const int* __restrict__ dst, const float* __restrict__ alpha,
                          float* __restrict__ m) {
    int e = blockIdx.x * blockDim.x + threadIdx.x;
    if (e < N_EDGES) atomicMaxFloat(&m[dst[e]], alpha[e]);
}

__global__ void exp_sum_k(const int* __restrict__ dst, float* __restrict__ alpha,
                          const float* __restrict__ m, float* __restrict__ denom) {
    int e = blockIdx.x * blockDim.x + threadIdx.x;
    if (e < N_EDGES) {
        float v = expf(alpha[e] - m[dst[e]]);
        alpha[e] = v;
        atomicAdd(&denom[dst[e]], v);
    }
}

// out[dst] += (ex/denom[dst]) * h[src]  — 2 edges per 256-thread block
__global__ void aggregate(const int* __restrict__ src, const int* __restrict__ dst,
                          const float* __restrict__ ex, const float* __restrict__ denom,
                          const float* __restrict__ h, float* __restrict__ out) {
    int tid = threadIdx.x;
    int e = blockIdx.x * 2 + (tid >> 7);
    int t = tid & 127;
    if (e >= N_EDGES) return;
    int d = dst[e];
    float w = ex[e] / fmaxf(denom[d], 1e-16f);
    atomicAdd(&out[(size_t)d * H_DIM + t], w * h[(size_t)src[e] * H_DIM + t]);
}

// pooled[g,t] = max over nodes of relu(agg[n,t]+b[t]); batch is sorted
__global__ void pool_max(const float* __restrict__ agg, const float* __restrict__ b,
                         const int* __restrict__ batch, float* __restrict__ pooled) {
    int t = threadIdx.x;  // 128
    int n0 = blockIdx.x * 64;
    int n1 = min(n0 + 64, N_NODES);
    if (n0 >= N_NODES) return;
    float bt = b[t];
    int cur = batch[n0];
    float acc = -INFINITY;
    for (int n = n0; n < n1; ++n) {
        int g = batch[n];
        if (g != cur) {
            atomicMaxFloat(&pooled[cur * H_DIM + t], acc);
            acc = -INFINITY;
            cur = g;
        }
        float v = fmaxf(agg[(size_t)n * H_DIM + t] + bt, 0.f);
        acc = fmaxf(acc, v);
    }
    atomicMaxFloat(&pooled[cur * H_DIM + t], acc);
}

__global__ void final_logits(const float* __restrict__ pooled, const float* __restrict__ Wl,
                             const float* __restrict__ bl, float* __restrict__ outp) {
    int g = threadIdx.x;  // 64
    if (g >= G_GRAPHS) return;
    float lg[C_CLS];
#pragma unroll
    for (int c = 0; c < C_CLS; ++c) lg[c] = bl[c];
    for (int k = 0; k < H_DIM; ++k) {
        float v = pooled[g * H_DIM + k];
        if (!(v > -3.0e38f)) v = 0.f;  // guard -inf (empty graph) and NaN
#pragma unroll
        for (int c = 0; c < C_CLS; ++c) lg[c] += v * Wl[k * C_CLS + c];
    }
    float mx = lg[0];
#pragma unroll
    for (int c = 1; c < C_CLS; ++c) mx = fmaxf(mx, lg[c]);
    float se = 0.f;
#pragma unroll
    for (int c = 0; c < C_CLS; ++c) se += expf(lg[c] - mx);
    float lse = logf(se);
#pragma unroll
    for (int c = 0; c < C_CLS; ++c) outp[g * C_CLS + c] = lg[c] - mx - lse;
}

extern "C" void kernel_launch(void* const* d_in, const int* in_sizes, int n_in,
                              void* d_out, int out_size, void* d_ws, size_t ws_size,
                              hipStream_t stream) {
    const float* x     = (const float*)d_in[0];
    const int*   eidx  = (const int*)d_in[1];
    const float* ea    = (const float*)d_in[2];
    const int*   batch = (const int*)d_in[3];
    const float* W1  = (const float*)d_in[4];
    const float* We1 = (const float*)d_in[5];
    const float* as1 = (const float*)d_in[6];
    const float* ad1 = (const float*)d_in[7];
    const float* ae1 = (const float*)d_in[8];
    const float* b1  = (const float*)d_in[9];
    const float* W2  = (const float*)d_in[10];
    const float* We2 = (const float*)d_in[11];
    const float* as2 = (const float*)d_in[12];
    const float* ad2 = (const float*)d_in[13];
    const float* ae2 = (const float*)d_in[14];
    const float* b2  = (const float*)d_in[15];
    const float* Wl  = (const float*)d_in[16];
    const float* bl  = (const float*)d_in[17];
    float* outp = (float*)d_out;

    const int* src = eidx;
    const int* dst = eidx + N_EDGES;

    float* ws = (float*)d_ws;
    size_t off = 0;
    float* h      = ws + off; off += (size_t)N_NODES * H_DIM;
    float* agg    = ws + off; off += (size_t)N_NODES * H_DIM;
    float* alpha  = ws + off; off += N_EDGES;
    float* m      = ws + off; off += N_NODES;
    float* denom  = ws + off; off += N_NODES;
    float* hs     = ws + off; off += N_NODES;
    float* hd     = ws + off; off += N_NODES;
    float* pooled = ws + off; off += G_GRAPHS * H_DIM;
    float* ve1    = ws + off; off += 16;
    float* ve2    = ws + off; off += 16;

    const int EB = (N_EDGES + 255) / 256;
    const int NB = (N_NODES + 255) / 256;

    compute_ve<<<1, 32, 0, stream>>>(We1, ae1, We2, ae2, ve1, ve2);

    // ---- conv1 ----
    init_nodes<<<NB, 256, 0, stream>>>(m, denom);
    hipMemsetAsync(agg, 0, (size_t)N_NODES * H_DIM * sizeof(float), stream);
    gemm_node<F_IN><<<N_NODES / 16, 128, 0, stream>>>(x, nullptr, W1, h);
    node_dots<<<N_NODES, 64, 0, stream>>>(h, as1, ad1, hs, hd);
    edge_alpha<<<EB, 256, 0, stream>>>(src, dst, ea, ve1, hs, hd, alpha);
    seg_max_k<<<EB, 256, 0, stream>>>(dst, alpha, m);
    exp_sum_k<<<EB, 256, 0, stream>>>(dst, alpha, m, denom);
    aggregate<<<N_EDGES / 2, 256, 0, stream>>>(src, dst, alpha, denom, h, agg);

    // ---- conv2 : input = relu(agg + b1) ----
    gemm_node<H_DIM><<<N_NODES / 16, 128, 0, stream>>>(agg, b1, W2, h);
    init_nodes<<<NB, 256, 0, stream>>>(m, denom);
    hipMemsetAsync(agg, 0, (size_t)N_NODES * H_DIM * sizeof(float), stream);
    node_dots<<<N_NODES, 64, 0, stream>>>(h, as2, ad2, hs, hd);
    edge_alpha<<<EB, 256, 0, stream>>>(src, dst, ea, ve2, hs, hd, alpha);
    seg_max_k<<<EB, 256, 0, stream>>>(dst, alpha, m);
    exp_sum_k<<<EB, 256, 0, stream>>>(dst, alpha, m, denom);
    aggregate<<<N_EDGES / 2, 256, 0, stream>>>(src, dst, alpha, denom, h, agg);

    // ---- pool + classifier ----
    init_pooled<<<(G_GRAPHS * H_DIM + 255) / 256, 256, 0, stream>>>(pooled);
    pool_max<<<(N_NODES + 63) / 64, 128, 0, stream>>>(agg, b2, batch, pooled);
    final_logits<<<1, 64, 0, stream>>>(pooled, Wl, bl, outp);
}

// Round 2
// 548.548 us; speedup vs baseline: 2.2019x; 2.2019x over previous
//
#include <hip/hip_runtime.h>
#include <math.h>

#define N_NODES 50000
#define N_EDGES 800000
#define F_IN    86
#define H_DIM   128
#define ED_DIM  16
#define C_CLS   18
#define G_GRAPHS 64
#define NEG_SLOPE 0.2f
#define SCAN_BLOCKS ((N_NODES + 255) / 256)   // 196

__device__ __forceinline__ void atomicMaxFloat(float* addr, float val) {
    if (val >= 0.0f) atomicMax((int*)addr, __float_as_int(val));
    else             atomicMin((unsigned int*)addr, __float_as_uint(val));
}

// ve[d] = sum_h We[d*H+h] * ae[h]   (collapses (ea@We)@ae to ea@ve)
__global__ void compute_ve(const float* __restrict__ We1, const float* __restrict__ ae1,
                           const float* __restrict__ We2, const float* __restrict__ ae2,
                           float* __restrict__ ve1, float* __restrict__ ve2) {
    int t = threadIdx.x;
    if (t < ED_DIM) {
        float s = 0.f;
        for (int h = 0; h < H_DIM; ++h) s += We1[t * H_DIM + h] * ae1[h];
        ve1[t] = s;
    } else if (t < 2 * ED_DIM) {
        int j = t - ED_DIM;
        float s = 0.f;
        for (int h = 0; h < H_DIM; ++h) s += We2[j * H_DIM + h] * ae2[h];
        ve2[j] = s;
    }
}

// dot1[e] = ea[e,:].ve1 ; dot2[e] = ea[e,:].ve2  (original edge order, coalesced)
__global__ void edge_dots(const float* __restrict__ ea,
                          const float* __restrict__ ve1, const float* __restrict__ ve2,
                          float* __restrict__ dot1, float* __restrict__ dot2) {
    int e = blockIdx.x * blockDim.x + threadIdx.x;
    if (e >= N_EDGES) return;
    const float4* p = (const float4*)(ea + (size_t)e * ED_DIM);
    float4 v0 = p[0], v1 = p[1], v2 = p[2], v3 = p[3];
    float s1 = v0.x*ve1[0] + v0.y*ve1[1] + v0.z*ve1[2] + v0.w*ve1[3]
             + v1.x*ve1[4] + v1.y*ve1[5] + v1.z*ve1[6] + v1.w*ve1[7]
             + v2.x*ve1[8] + v2.y*ve1[9] + v2.z*ve1[10] + v2.w*ve1[11]
             + v3.x*ve1[12] + v3.y*ve1[13] + v3.z*ve1[14] + v3.w*ve1[15];
    float s2 = v0.x*ve2[0] + v0.y*ve2[1] + v0.z*ve2[2] + v0.w*ve2[3]
             + v1.x*ve2[4] + v1.y*ve2[5] + v1.z*ve2[6] + v1.w*ve2[7]
             + v2.x*ve2[8] + v2.y*ve2[9] + v2.z*ve2[10] + v2.w*ve2[11]
             + v3.x*ve2[12] + v3.y*ve2[13] + v3.z*ve2[14] + v3.w*ve2[15];
    dot1[e] = s1;
    dot2[e] = s2;
}

// ---- CSR build: histogram + scan + scatter ----
__global__ void hist_dst(const int* __restrict__ dst, int* __restrict__ cnt) {
    int e = blockIdx.x * blockDim.x + threadIdx.x;
    if (e < N_EDGES) atomicAdd(&cnt[dst[e]], 1);
}

__global__ void scan1(const int* __restrict__ cnt, int* __restrict__ excl,
                      int* __restrict__ bsum) {
    __shared__ int s[256];
    int tid = threadIdx.x;
    int i = blockIdx.x * 256 + tid;
    int v = (i < N_NODES) ? cnt[i] : 0;
    s[tid] = v;
    __syncthreads();
    for (int o = 1; o < 256; o <<= 1) {
        int t = (tid >= o) ? s[tid - o] : 0;
        __syncthreads();
        s[tid] += t;
        __syncthreads();
    }
    if (i < N_NODES) excl[i] = s[tid] - v;     // exclusive within block
    if (tid == 255) bsum[blockIdx.x] = s[255];
}

__global__ void scan2(int* __restrict__ bsum) {
    __shared__ int s[256];
    int tid = threadIdx.x;
    int v = (tid < SCAN_BLOCKS) ? bsum[tid] : 0;
    s[tid] = v;
    __syncthreads();
    for (int o = 1; o < 256; o <<= 1) {
        int t = (tid >= o) ? s[tid - o] : 0;
        __syncthreads();
        s[tid] += t;
        __syncthreads();
    }
    if (tid < SCAN_BLOCKS) bsum[tid] = s[tid] - v;  // exclusive
}

__global__ void scan3(const int* __restrict__ excl, const int* __restrict__ bsum,
                      int* __restrict__ row_ptr, int* __restrict__ fill) {
    int i = blockIdx.x * 256 + threadIdx.x;
    if (i < N_NODES) {
        int r = excl[i] + bsum[blockIdx.x];
        row_ptr[i] = r;
        fill[i] = r;
    }
    if (i == 0) row_ptr[N_NODES] = N_EDGES;
}

__global__ void scatter_edges(const int* __restrict__ src, const int* __restrict__ dst,
                              int* __restrict__ fill,
                              int* __restrict__ src_perm, int* __restrict__ eid_perm) {
    int e = blockIdx.x * blockDim.x + threadIdx.x;
    if (e >= N_EDGES) return;
    int pos = atomicAdd(&fill[dst[e]], 1);
    src_perm[pos] = src[e];
    eid_perm[pos] = e;
}

// h[n,:] = act(in[n,:]) @ W    where act = relu(x + bias) if bias != null else x
template<int K>
__global__ void gemm_node(const float* __restrict__ in, const float* __restrict__ bias,
                          const float* __restrict__ W, float* __restrict__ h) {
    __shared__ float xs[16 * K];
    int t = threadIdx.x;
    int n0 = blockIdx.x * 16;
    for (int idx = t; idx < 16 * K; idx += 128) {
        int r = idx / K, k = idx % K;
        float v = in[(size_t)(n0 + r) * K + k];
        if (bias) v = fmaxf(v + bias[k], 0.f);
        xs[idx] = v;
    }
    __syncthreads();
    float acc[16];
#pragma unroll
    for (int r = 0; r < 16; ++r) acc[r] = 0.f;
#pragma unroll 2
    for (int k = 0; k < K; ++k) {
        float w = W[k * H_DIM + t];
#pragma unroll
        for (int r = 0; r < 16; ++r) acc[r] += xs[r * K + k] * w;
    }
#pragma unroll
    for (int r = 0; r < 16; ++r) h[(size_t)(n0 + r) * H_DIM + t] = acc[r];
}

// hs[n] = h[n,:].a_src ; hd[n] = h[n,:].a_dst  — one wave per node
__global__ void node_dots(const float* __restrict__ h,
                          const float* __restrict__ a_s, const float* __restrict__ a_d,
                          float* __restrict__ hs, float* __restrict__ hd) {
    int n = blockIdx.x * 4 + (threadIdx.x >> 6);
    int t = threadIdx.x & 63;
    if (n >= N_NODES) return;
    float v0 = h[(size_t)n * H_DIM + t];
    float v1 = h[(size_t)n * H_DIM + t + 64];
    float ss = v0 * a_s[t] + v1 * a_s[t + 64];
    float sd = v0 * a_d[t] + v1 * a_d[t + 64];
    for (int o = 32; o > 0; o >>= 1) {
        ss += __shfl_down(ss, o);
        sd += __shfl_down(sd, o);
    }
    if (t == 0) { hs[n] = ss; hd[n] = sd; }
}

// One wave per dst node: alpha -> softmax -> weighted sum of h[src] rows.
// No atomics anywhere. Lane l owns output dims l and l+64.
__global__ void gat_node(const int* __restrict__ row_ptr,
                         const int* __restrict__ src_perm, const int* __restrict__ eid_perm,
                         const float* __restrict__ dotv,
                         const float* __restrict__ hs, const float* __restrict__ hd,
                         const float* __restrict__ h, float* __restrict__ out) {
    int n = blockIdx.x * 4 + (threadIdx.x >> 6);
    int lane = threadIdx.x & 63;
    if (n >= N_NODES) return;
    int r0 = row_ptr[n], r1 = row_ptr[n + 1];
    float hdn = hd[n];

    // pass 1: segment max
    float mx = -INFINITY;
    for (int c = r0; c < r1; c += 64) {
        int i = c + lane;
        float a = -INFINITY;
        if (i < r1) {
            float t = hs[src_perm[i]] + hdn + dotv[eid_perm[i]];
            a = (t > 0.f) ? t : NEG_SLOPE * t;
        }
        mx = fmaxf(mx, a);
    }
#pragma unroll
    for (int o = 32; o > 0; o >>= 1) mx = fmaxf(mx, __shfl_xor(mx, o));

    // pass 2: exp weights + unnormalized accumulate; divide at the end
    float acc0 = 0.f, acc1 = 0.f, den = 0.f;
    for (int c = r0; c < r1; c += 64) {
        int i = c + lane;
        float w = 0.f;
        int s = 0;
        if (i < r1) {
            float t = hs[src_perm[i]] + hdn + dotv[eid_perm[i]];
            t = (t > 0.f) ? t : NEG_SLOPE * t;
            w = expf(t - mx);
            s = src_perm[i];
        }
        float wsum = w;
#pragma unroll
        for (int o = 32; o > 0; o >>= 1) wsum += __shfl_xor(wsum, o);
        den += wsum;
        int lim = min(64, r1 - c);
        for (int j = 0; j < lim; ++j) {
            float wj = __shfl(w, j);
            int sj = __shfl(s, j);
            const float* hp = h + (size_t)sj * H_DIM;
            acc0 += wj * hp[lane];
            acc1 += wj * hp[lane + 64];
        }
    }
    float inv = 1.f / fmaxf(den, 1e-16f);
    out[(size_t)n * H_DIM + lane]      = acc0 * inv;
    out[(size_t)n * H_DIM + lane + 64] = acc1 * inv;
}

__global__ void init_pooled(float* __restrict__ pooled) {
    int i = blockIdx.x * blockDim.x + threadIdx.x;
    if (i < G_GRAPHS * H_DIM) pooled[i] = -INFINITY;
}

// pooled[g,t] = max over nodes of relu(agg[n,t]+b[t]); batch is sorted
__global__ void pool_max(const float* __restrict__ agg, const float* __restrict__ b,
                         const int* __restrict__ batch, float* __restrict__ pooled) {
    int t = threadIdx.x;  // 128
    int n0 = blockIdx.x * 64;
    int n1 = min(n0 + 64, N_NODES);
    if (n0 >= N_NODES) return;
    float bt = b[t];
    int cur = batch[n0];
    float acc = -INFINITY;
    for (int n = n0; n < n1; ++n) {
        int g = batch[n];
        if (g != cur) {
            atomicMaxFloat(&pooled[cur * H_DIM + t], acc);
            acc = -INFINITY;
            cur = g;
        }
        float v = fmaxf(agg[(size_t)n * H_DIM + t] + bt, 0.f);
        acc = fmaxf(acc, v);
    }
    atomicMaxFloat(&pooled[cur * H_DIM + t], acc);
}

__global__ void final_logits(const float* __restrict__ pooled, const float* __restrict__ Wl,
                             const float* __restrict__ bl, float* __restrict__ outp) {
    int g = threadIdx.x;  // 64
    if (g >= G_GRAPHS) return;
    float lg[C_CLS];
#pragma unroll
    for (int c = 0; c < C_CLS; ++c) lg[c] = bl[c];
    for (int k = 0; k < H_DIM; ++k) {
        float v = pooled[g * H_DIM + k];
        if (!(v > -3.0e38f)) v = 0.f;  // guard -inf (empty graph) and NaN
#pragma unroll
        for (int c = 0; c < C_CLS; ++c) lg[c] += v * Wl[k * C_CLS + c];
    }
    float mx = lg[0];
#pragma unroll
    for (int c = 1; c < C_CLS; ++c) mx = fmaxf(mx, lg[c]);
    float se = 0.f;
#pragma unroll
    for (int c = 0; c < C_CLS; ++c) se += expf(lg[c] - mx);
    float lse = logf(se);
#pragma unroll
    for (int c = 0; c < C_CLS; ++c) outp[g * C_CLS + c] = lg[c] - mx - lse;
}

extern "C" void kernel_launch(void* const* d_in, const int* in_sizes, int n_in,
                              void* d_out, int out_size, void* d_ws, size_t ws_size,
                              hipStream_t stream) {
    const float* x     = (const float*)d_in[0];
    const int*   eidx  = (const int*)d_in[1];
    const float* ea    = (const float*)d_in[2];
    const int*   batch = (const int*)d_in[3];
    const float* W1  = (const float*)d_in[4];
    const float* We1 = (const float*)d_in[5];
    const float* as1 = (const float*)d_in[6];
    const float* ad1 = (const float*)d_in[7];
    const float* ae1 = (const float*)d_in[8];
    const float* b1  = (const float*)d_in[9];
    const float* W2  = (const float*)d_in[10];
    const float* We2 = (const float*)d_in[11];
    const float* as2 = (const float*)d_in[12];
    const float* ad2 = (const float*)d_in[13];
    const float* ae2 = (const float*)d_in[14];
    const float* b2  = (const float*)d_in[15];
    const float* Wl  = (const float*)d_in[16];
    const float* bl  = (const float*)d_in[17];
    float* outp = (float*)d_out;

    const int* src = eidx;
    const int* dst = eidx + N_EDGES;

    char* wsb = (char*)d_ws;
    size_t off = 0;
    auto alloc = [&](size_t bytes) { char* p = wsb + off; off += (bytes + 255) & ~(size_t)255; return p; };
    float* h        = (float*)alloc((size_t)N_NODES * H_DIM * 4);
    float* agg      = (float*)alloc((size_t)N_NODES * H_DIM * 4);
    float* hs       = (float*)alloc(N_NODES * 4);
    float* hd       = (float*)alloc(N_NODES * 4);
    int*   row_ptr  = (int*)alloc((N_NODES + 1) * 4);
    int*   fill     = (int*)alloc(N_NODES * 4);
    int*   cnt      = (int*)alloc(N_NODES * 4);
    int*   excl     = (int*)alloc(N_NODES * 4);
    int*   bsum     = (int*)alloc(SCAN_BLOCKS * 4);
    int*   src_perm = (int*)alloc((size_t)N_EDGES * 4);
    int*   eid_perm = (int*)alloc((size_t)N_EDGES * 4);
    float* dot1     = (float*)alloc((size_t)N_EDGES * 4);
    float* dot2     = (float*)alloc((size_t)N_EDGES * 4);
    float* pooled   = (float*)alloc(G_GRAPHS * H_DIM * 4);
    float* ve1      = (float*)alloc(16 * 4);
    float* ve2      = (float*)alloc(16 * 4);

    const int EB = (N_EDGES + 255) / 256;

    // small precomputes + CSR build
    compute_ve<<<1, 32, 0, stream>>>(We1, ae1, We2, ae2, ve1, ve2);
    edge_dots<<<EB, 256, 0, stream>>>(ea, ve1, ve2, dot1, dot2);
    hipMemsetAsync(cnt, 0, N_NODES * 4, stream);
    hist_dst<<<EB, 256, 0, stream>>>(dst, cnt);
    scan1<<<SCAN_BLOCKS, 256, 0, stream>>>(cnt, excl, bsum);
    scan2<<<1, 256, 0, stream>>>(bsum);
    scan3<<<SCAN_BLOCKS, 256, 0, stream>>>(excl, bsum, row_ptr, fill);
    scatter_edges<<<EB, 256, 0, stream>>>(src, dst, fill, src_perm, eid_perm);

    const int NB4 = (N_NODES + 3) / 4;

    // ---- conv1 ----
    gemm_node<F_IN><<<N_NODES / 16, 128, 0, stream>>>(x, nullptr, W1, h);
    node_dots<<<NB4, 256, 0, stream>>>(h, as1, ad1, hs, hd);
    gat_node<<<NB4, 256, 0, stream>>>(row_ptr, src_perm, eid_perm, dot1, hs, hd, h, agg);

    // ---- conv2 : input = relu(agg + b1) ----
    gemm_node<H_DIM><<<N_NODES / 16, 128, 0, stream>>>(agg, b1, W2, h);
    node_dots<<<NB4, 256, 0, stream>>>(h, as2, ad2, hs, hd);
    gat_node<<<NB4, 256, 0, stream>>>(row_ptr, src_perm, eid_perm, dot2, hs, hd, h, agg);

    // ---- pool + classifier ----
    init_pooled<<<(G_GRAPHS * H_DIM + 255) / 256, 256, 0, stream>>>(pooled);
    pool_max<<<(N_NODES + 63) / 64, 128, 0, stream>>>(agg, b2, batch, pooled);
    final_logits<<<1, 64, 0, stream>>>(pooled, Wl, bl, outp);
}

// Round 3
// 436.561 us; speedup vs baseline: 2.7667x; 1.2565x over previous
//
#include <hip/hip_runtime.h>
#include <math.h>

#define N_NODES 50000
#define N_EDGES 800000
#define F_IN    86
#define H_DIM   128
#define ED_DIM  16
#define C_CLS   18
#define G_GRAPHS 64
#define NEG_SLOPE 0.2f
#define SCAN_BLOCKS ((N_NODES + 255) / 256)   // 196

typedef _Float16 h2v  __attribute__((ext_vector_type(2)));
typedef _Float16 half8 __attribute__((ext_vector_type(8)));
typedef float    f4v  __attribute__((ext_vector_type(4)));

__device__ __forceinline__ void atomicMaxFloat(float* addr, float val) {
    if (val >= 0.0f) atomicMax((int*)addr, __float_as_int(val));
    else             atomicMin((unsigned int*)addr, __float_as_uint(val));
}

// ve[d] = sum_h We[d*H+h] * ae[h]   (collapses (ea@We)@ae to ea@ve)
__global__ void compute_ve(const float* __restrict__ We1, const float* __restrict__ ae1,
                           const float* __restrict__ We2, const float* __restrict__ ae2,
                           float* __restrict__ ve1, float* __restrict__ ve2) {
    int t = threadIdx.x;
    if (t < ED_DIM) {
        float s = 0.f;
        for (int h = 0; h < H_DIM; ++h) s += We1[t * H_DIM + h] * ae1[h];
        ve1[t] = s;
    } else if (t < 2 * ED_DIM) {
        int j = t - ED_DIM;
        float s = 0.f;
        for (int h = 0; h < H_DIM; ++h) s += We2[j * H_DIM + h] * ae2[h];
        ve2[j] = s;
    }
}

// ---- CSR build ----
__global__ void hist_dst(const int* __restrict__ dst, int* __restrict__ cnt) {
    int e = blockIdx.x * blockDim.x + threadIdx.x;
    if (e < N_EDGES) atomicAdd(&cnt[dst[e]], 1);
}

__global__ void scan1(const int* __restrict__ cnt, int* __restrict__ excl,
                      int* __restrict__ bsum) {
    __shared__ int s[256];
    int tid = threadIdx.x;
    int i = blockIdx.x * 256 + tid;
    int v = (i < N_NODES) ? cnt[i] : 0;
    s[tid] = v;
    __syncthreads();
    for (int o = 1; o < 256; o <<= 1) {
        int t = (tid >= o) ? s[tid - o] : 0;
        __syncthreads();
        s[tid] += t;
        __syncthreads();
    }
    if (i < N_NODES) excl[i] = s[tid] - v;
    if (tid == 255) bsum[blockIdx.x] = s[255];
}

__global__ void scan2(int* __restrict__ bsum) {
    __shared__ int s[256];
    int tid = threadIdx.x;
    int v = (tid < SCAN_BLOCKS) ? bsum[tid] : 0;
    s[tid] = v;
    __syncthreads();
    for (int o = 1; o < 256; o <<= 1) {
        int t = (tid >= o) ? s[tid - o] : 0;
        __syncthreads();
        s[tid] += t;
        __syncthreads();
    }
    if (tid < SCAN_BLOCKS) bsum[tid] = s[tid] - v;
}

__global__ void scan3(const int* __restrict__ excl, const int* __restrict__ bsum,
                      int* __restrict__ row_ptr, int* __restrict__ fill) {
    int i = blockIdx.x * 256 + threadIdx.x;
    if (i < N_NODES) {
        int r = excl[i] + bsum[blockIdx.x];
        row_ptr[i] = r;
        fill[i] = r;
    }
    if (i == 0) row_ptr[N_NODES] = N_EDGES;
}

// scatter edges sorted-by-dst; pack {src, dot1, dot2} per edge (dots fused here)
__global__ void scatter_edges(const int* __restrict__ src, const int* __restrict__ dst,
                              const float* __restrict__ ea,
                              const float* __restrict__ ve1, const float* __restrict__ ve2,
                              int* __restrict__ fill, int4* __restrict__ perm) {
    int e = blockIdx.x * blockDim.x + threadIdx.x;
    if (e >= N_EDGES) return;
    const float4* p = (const float4*)(ea + (size_t)e * ED_DIM);
    float4 v0 = p[0], v1 = p[1], v2 = p[2], v3 = p[3];
    float s1 = v0.x*ve1[0] + v0.y*ve1[1] + v0.z*ve1[2] + v0.w*ve1[3]
             + v1.x*ve1[4] + v1.y*ve1[5] + v1.z*ve1[6] + v1.w*ve1[7]
             + v2.x*ve1[8] + v2.y*ve1[9] + v2.z*ve1[10] + v2.w*ve1[11]
             + v3.x*ve1[12] + v3.y*ve1[13] + v3.z*ve1[14] + v3.w*ve1[15];
    float s2 = v0.x*ve2[0] + v0.y*ve2[1] + v0.z*ve2[2] + v0.w*ve2[3]
             + v1.x*ve2[4] + v1.y*ve2[5] + v1.z*ve2[6] + v1.w*ve2[7]
             + v2.x*ve2[8] + v2.y*ve2[9] + v2.z*ve2[10] + v2.w*ve2[11]
             + v3.x*ve2[12] + v3.y*ve2[13] + v3.z*ve2[14] + v3.w*ve2[15];
    int pos = atomicAdd(&fill[dst[e]], 1);
    perm[pos] = make_int4(src[e], __float_as_int(s1), __float_as_int(s2), 0);
}

// MFMA GEMM: hout[n, 0:128] = fp16( in[n, 0:K] @ W[K,128] ), K zero-padded to KLOG.
// Block: 256 thr = 4 waves (2x2), tile 64 rows x 128 cols. 16x16x32 f16 MFMA.
// A-frag: A[m=lane&15][k=quad*8+j]; B-frag: B[k=quad*8+j][n=lane&15] (B^T in LDS);
// C/D: col=lane&15, row=quad*4+reg  (guide-verified layouts).
template<typename T, int K, int KLOG, int KP>
__global__ __launch_bounds__(256)
void gemm_mfma(const T* __restrict__ in, const float* __restrict__ W,
               _Float16* __restrict__ hout) {
    __shared__ __attribute__((aligned(16))) _Float16 Asm[64 * KP];
    __shared__ __attribute__((aligned(16))) _Float16 Bsm[128 * KP];
    int tid = threadIdx.x;
    int n0 = blockIdx.x * 64;

    for (int idx = tid; idx < 64 * K; idx += 256) {
        int r = idx / K, k = idx - r * K;
        int row = n0 + r;
        float v = (row < N_NODES) ? (float)in[(size_t)row * K + k] : 0.f;
        Asm[r * KP + k] = (_Float16)v;
    }
    if constexpr (KLOG > K) {
        constexpr int PADW = KLOG - K;
        for (int idx = tid; idx < 64 * PADW; idx += 256) {
            int r = idx / PADW, k = K + (idx - r * PADW);
            Asm[r * KP + k] = (_Float16)0.f;
        }
    }
    for (int idx = tid; idx < K * 128; idx += 256) {
        int k = idx >> 7, n = idx & 127;
        Bsm[n * KP + k] = (_Float16)W[idx];
    }
    if constexpr (KLOG > K) {
        constexpr int PADW = KLOG - K;
        for (int idx = tid; idx < 128 * PADW; idx += 256) {
            int n = idx / PADW, k = K + (idx - n * PADW);
            Bsm[n * KP + k] = (_Float16)0.f;
        }
    }
    __syncthreads();

    int wave = tid >> 6, lane = tid & 63;
    int wm = (wave & 1) * 32, wn = (wave >> 1) * 64;
    int m16 = lane & 15, quad = lane >> 4;

    f4v acc[2][4];
#pragma unroll
    for (int t = 0; t < 2; ++t)
#pragma unroll
        for (int c = 0; c < 4; ++c) acc[t][c] = (f4v){0.f, 0.f, 0.f, 0.f};

#pragma unroll
    for (int kk = 0; kk < KLOG / 32; ++kk) {
        int koff = kk * 32 + quad * 8;
        half8 a0 = *(const half8*)&Asm[(wm + m16) * KP + koff];
        half8 a1 = *(const half8*)&Asm[(wm + 16 + m16) * KP + koff];
#pragma unroll
        for (int c = 0; c < 4; ++c) {
            half8 b = *(const half8*)&Bsm[(wn + c * 16 + m16) * KP + koff];
            acc[0][c] = __builtin_amdgcn_mfma_f32_16x16x32_f16(a0, b, acc[0][c], 0, 0, 0);
            acc[1][c] = __builtin_amdgcn_mfma_f32_16x16x32_f16(a1, b, acc[1][c], 0, 0, 0);
        }
    }

#pragma unroll
    for (int t = 0; t < 2; ++t)
#pragma unroll
        for (int c = 0; c < 4; ++c)
#pragma unroll
            for (int r = 0; r < 4; ++r) {
                int row = n0 + wm + t * 16 + quad * 4 + r;
                if (row < N_NODES)
                    hout[(size_t)row * H_DIM + wn + c * 16 + m16] = (_Float16)acc[t][c][r];
            }
}

// hs[n]=h[n,:].a_s ; hd[n]=h[n,:].a_d — one wave/node, lane l owns dims 2l,2l+1
__global__ void node_dots(const _Float16* __restrict__ h,
                          const float* __restrict__ a_s, const float* __restrict__ a_d,
                          float* __restrict__ hs, float* __restrict__ hd) {
    int n = blockIdx.x * 4 + (threadIdx.x >> 6);
    int l = threadIdx.x & 63;
    if (n >= N_NODES) return;
    h2v v = *(const h2v*)&h[(size_t)n * H_DIM + 2 * l];
    float2 a = ((const float2*)a_s)[l];
    float2 b = ((const float2*)a_d)[l];
    float f0 = (float)v.x, f1 = (float)v.y;
    float ss = f0 * a.x + f1 * a.y;
    float sd = f0 * b.x + f1 * b.y;
    for (int o = 32; o > 0; o >>= 1) {
        ss += __shfl_down(ss, o);
        sd += __shfl_down(sd, o);
    }
    if (l == 0) { hs[n] = ss; hd[n] = sd; }
}

// One wave per dst node, single pass (softmax without max-subtract: |alpha|<~10).
// out = fp16(relu(weighted_mean + bias)). Lane l owns dims 2l, 2l+1.
template<int DOT>
__global__ void gat_node(const int* __restrict__ row_ptr, const int4* __restrict__ perm,
                         const float* __restrict__ hs, const float* __restrict__ hd,
                         const _Float16* __restrict__ h, const float* __restrict__ bias,
                         _Float16* __restrict__ out) {
    int n = blockIdx.x * 4 + (threadIdx.x >> 6);
    int lane = threadIdx.x & 63;
    if (n >= N_NODES) return;
    int r0 = row_ptr[n], r1 = row_ptr[n + 1];
    float hdn = hd[n];

    float acc0 = 0.f, acc1 = 0.f, denl = 0.f;
    for (int c = r0; c < r1; c += 64) {
        int i = c + lane;
        float w = 0.f;
        int s = 0;
        if (i < r1) {
            int4 p = perm[i];
            s = p.x;
            float dotv = __int_as_float(DOT == 1 ? p.y : p.z);
            float t = hs[s] + hdn + dotv;
            t = (t > 0.f) ? t : NEG_SLOPE * t;
            w = expf(t);
        }
        denl += w;
        int lim = min(64, r1 - c);
        for (int j = 0; j < lim; ++j) {
            float wj = __shfl(w, j);
            int sj = __shfl(s, j);
            h2v v = *(const h2v*)&h[(size_t)sj * H_DIM + 2 * lane];
            acc0 += wj * (float)v.x;
            acc1 += wj * (float)v.y;
        }
    }
    float den = denl;
#pragma unroll
    for (int o = 32; o > 0; o >>= 1) den += __shfl_xor(den, o);
    float inv = 1.f / fmaxf(den, 1e-16f);
    float2 bv = ((const float2*)bias)[lane];
    h2v ov;
    ov.x = (_Float16)fmaxf(acc0 * inv + bv.x, 0.f);
    ov.y = (_Float16)fmaxf(acc1 * inv + bv.y, 0.f);
    *(h2v*)&out[(size_t)n * H_DIM + 2 * lane] = ov;
}

// pooled[g,t] = max over nodes of P[n,t]; P>=0 (relu'd), pooled pre-zeroed
__global__ void pool_max(const _Float16* __restrict__ P,
                         const int* __restrict__ batch, float* __restrict__ pooled) {
    int t = threadIdx.x;  // 128
    int n0 = blockIdx.x * 64;
    int n1 = min(n0 + 64, N_NODES);
    if (n0 >= N_NODES) return;
    int cur = batch[n0];
    float acc = 0.f;
    for (int n = n0; n < n1; ++n) {
        int g = batch[n];
        if (g != cur) {
            atomicMaxFloat(&pooled[cur * H_DIM + t], acc);
            acc = 0.f;
            cur = g;
        }
        acc = fmaxf(acc, (float)P[(size_t)n * H_DIM + t]);
    }
    atomicMaxFloat(&pooled[cur * H_DIM + t], acc);
}

__global__ void final_logits(const float* __restrict__ pooled, const float* __restrict__ Wl,
                             const float* __restrict__ bl, float* __restrict__ outp) {
    int g = threadIdx.x;  // 64
    if (g >= G_GRAPHS) return;
    float lg[C_CLS];
#pragma unroll
    for (int c = 0; c < C_CLS; ++c) lg[c] = bl[c];
    for (int k = 0; k < H_DIM; ++k) {
        float v = pooled[g * H_DIM + k];
#pragma unroll
        for (int c = 0; c < C_CLS; ++c) lg[c] += v * Wl[k * C_CLS + c];
    }
    float mx = lg[0];
#pragma unroll
    for (int c = 1; c < C_CLS; ++c) mx = fmaxf(mx, lg[c]);
    float se = 0.f;
#pragma unroll
    for (int c = 0; c < C_CLS; ++c) se += expf(lg[c] - mx);
    float lse = logf(se);
#pragma unroll
    for (int c = 0; c < C_CLS; ++c) outp[g * C_CLS + c] = lg[c] - mx - lse;
}

extern "C" void kernel_launch(void* const* d_in, const int* in_sizes, int n_in,
                              void* d_out, int out_size, void* d_ws, size_t ws_size,
                              hipStream_t stream) {
    const float* x     = (const float*)d_in[0];
    const int*   eidx  = (const int*)d_in[1];
    const float* ea    = (const float*)d_in[2];
    const int*   batch = (const int*)d_in[3];
    const float* W1  = (const float*)d_in[4];
    const float* We1 = (const float*)d_in[5];
    const float* as1 = (const float*)d_in[6];
    const float* ad1 = (const float*)d_in[7];
    const float* ae1 = (const float*)d_in[8];
    const float* b1  = (const float*)d_in[9];
    const float* W2  = (const float*)d_in[10];
    const float* We2 = (const float*)d_in[11];
    const float* as2 = (const float*)d_in[12];
    const float* ad2 = (const float*)d_in[13];
    const float* ae2 = (const float*)d_in[14];
    const float* b2  = (const float*)d_in[15];
    const float* Wl  = (const float*)d_in[16];
    const float* bl  = (const float*)d_in[17];
    float* outp = (float*)d_out;

    const int* src = eidx;
    const int* dst = eidx + N_EDGES;

    char* wsb = (char*)d_ws;
    size_t off = 0;
    auto alloc = [&](size_t bytes) { char* p = wsb + off; off += (bytes + 255) & ~(size_t)255; return p; };
    _Float16* h    = (_Float16*)alloc((size_t)N_NODES * H_DIM * 2);
    _Float16* A2   = (_Float16*)alloc((size_t)N_NODES * H_DIM * 2);
    _Float16* P    = (_Float16*)alloc((size_t)N_NODES * H_DIM * 2);
    int4*  perm    = (int4*)alloc((size_t)N_EDGES * 16);
    float* hs      = (float*)alloc(N_NODES * 4);
    float* hd      = (float*)alloc(N_NODES * 4);
    int*   row_ptr = (int*)alloc((N_NODES + 1) * 4);
    int*   fill    = (int*)alloc(N_NODES * 4);
    int*   cnt     = (int*)alloc(N_NODES * 4);
    int*   excl    = (int*)alloc(N_NODES * 4);
    int*   bsum    = (int*)alloc(SCAN_BLOCKS * 4);
    float* pooled  = (float*)alloc(G_GRAPHS * H_DIM * 4);
    float* ve1     = (float*)alloc(16 * 4);
    float* ve2     = (float*)alloc(16 * 4);

    const int EB = (N_EDGES + 255) / 256;
    const int NB4 = (N_NODES + 3) / 4;
    const int GB = (N_NODES + 63) / 64;   // 782 gemm blocks

    // precompute + CSR build (edge dots fused into scatter)
    compute_ve<<<1, 32, 0, stream>>>(We1, ae1, We2, ae2, ve1, ve2);
    hipMemsetAsync(cnt, 0, N_NODES * 4, stream);
    hist_dst<<<EB, 256, 0, stream>>>(dst, cnt);
    scan1<<<SCAN_BLOCKS, 256, 0, stream>>>(cnt, excl, bsum);
    scan2<<<1, 256, 0, stream>>>(bsum);
    scan3<<<SCAN_BLOCKS, 256, 0, stream>>>(excl, bsum, row_ptr, fill);
    scatter_edges<<<EB, 256, 0, stream>>>(src, dst, ea, ve1, ve2, fill, perm);

    // ---- conv1 ----
    gemm_mfma<float, F_IN, 96, 104><<<GB, 256, 0, stream>>>(x, W1, h);
    node_dots<<<NB4, 256, 0, stream>>>(h, as1, ad1, hs, hd);
    gat_node<1><<<NB4, 256, 0, stream>>>(row_ptr, perm, hs, hd, h, b1, A2);

    // ---- conv2 ----
    gemm_mfma<_Float16, H_DIM, 128, 136><<<GB, 256, 0, stream>>>(A2, W2, h);
    node_dots<<<NB4, 256, 0, stream>>>(h, as2, ad2, hs, hd);
    gat_node<2><<<NB4, 256, 0, stream>>>(row_ptr, perm, hs, hd, h, b2, P);

    // ---- pool + classifier ----
    hipMemsetAsync(pooled, 0, G_GRAPHS * H_DIM * 4, stream);
    pool_max<<<GB, 128, 0, stream>>>(P, batch, pooled);
    final_logits<<<1, 64, 0, stream>>>(pooled, Wl, bl, outp);
}

// Round 4
// 386.808 us; speedup vs baseline: 3.1226x; 1.1286x over previous
//
#include <hip/hip_runtime.h>
#include <math.h>

#define N_NODES 50000
#define N_EDGES 800000
#define F_IN    86
#define H_DIM   128
#define ED_DIM  16
#define C_CLS   18
#define G_GRAPHS 64
#define NEG_SLOPE 0.2f
#define SCAN_BLOCKS ((N_NODES + 255) / 256)   // 196

typedef _Float16 h2v   __attribute__((ext_vector_type(2)));
typedef _Float16 half8 __attribute__((ext_vector_type(8)));
typedef float    f4v   __attribute__((ext_vector_type(4)));

__device__ __forceinline__ void atomicMaxFloat(float* addr, float val) {
    if (val >= 0.0f) atomicMax((int*)addr, __float_as_int(val));
    else             atomicMin((unsigned int*)addr, __float_as_uint(val));
}

// One kernel: zero cnt (blocks 0..SCAN_BLOCKS-1), compute ve1/ve2 + zero pooled
// (block SCAN_BLOCKS).
__global__ void prep(int* __restrict__ cnt, float* __restrict__ pooled,
                     const float* __restrict__ We1, const float* __restrict__ ae1,
                     const float* __restrict__ We2, const float* __restrict__ ae2,
                     float* __restrict__ ve1, float* __restrict__ ve2) {
    int b = blockIdx.x, t = threadIdx.x;
    if (b < SCAN_BLOCKS) {
        int i = b * 256 + t;
        if (i < N_NODES) cnt[i] = 0;
    } else {
        if (t < ED_DIM) {
            float s = 0.f;
            for (int h = 0; h < H_DIM; ++h) s += We1[t * H_DIM + h] * ae1[h];
            ve1[t] = s;
        } else if (t < 2 * ED_DIM) {
            int j = t - ED_DIM;
            float s = 0.f;
            for (int h = 0; h < H_DIM; ++h) s += We2[j * H_DIM + h] * ae2[h];
            ve2[j] = s;
        }
        for (int i = t; i < G_GRAPHS * H_DIM; i += 256) pooled[i] = 0.f;
    }
}

// ---- CSR build ----
__global__ void hist_dst(const int* __restrict__ dst, int* __restrict__ cnt) {
    int e = blockIdx.x * blockDim.x + threadIdx.x;
    if (e < N_EDGES) atomicAdd(&cnt[dst[e]], 1);
}

__global__ void scan1(const int* __restrict__ cnt, int* __restrict__ excl,
                      int* __restrict__ bsum) {
    __shared__ int s[256];
    int tid = threadIdx.x;
    int i = blockIdx.x * 256 + tid;
    int v = (i < N_NODES) ? cnt[i] : 0;
    s[tid] = v;
    __syncthreads();
    for (int o = 1; o < 256; o <<= 1) {
        int t = (tid >= o) ? s[tid - o] : 0;
        __syncthreads();
        s[tid] += t;
        __syncthreads();
    }
    if (i < N_NODES) excl[i] = s[tid] - v;
    if (tid == 255) bsum[blockIdx.x] = s[255];
}

__global__ void scan2(int* __restrict__ bsum) {
    __shared__ int s[256];
    int tid = threadIdx.x;
    int v = (tid < SCAN_BLOCKS) ? bsum[tid] : 0;
    s[tid] = v;
    __syncthreads();
    for (int o = 1; o < 256; o <<= 1) {
        int t = (tid >= o) ? s[tid - o] : 0;
        __syncthreads();
        s[tid] += t;
        __syncthreads();
    }
    if (tid < SCAN_BLOCKS) bsum[tid] = s[tid] - v;
}

__global__ void scan3(const int* __restrict__ excl, const int* __restrict__ bsum,
                      int* __restrict__ row_ptr, int* __restrict__ fill) {
    int i = blockIdx.x * 256 + threadIdx.x;
    if (i < N_NODES) {
        int r = excl[i] + bsum[blockIdx.x];
        row_ptr[i] = r;
        fill[i] = r;
    }
    if (i == 0) row_ptr[N_NODES] = N_EDGES;
}

// scatter edges sorted-by-dst; pack {src, dot1, dot2} per edge
__global__ void scatter_edges(const int* __restrict__ src, const int* __restrict__ dst,
                              const float* __restrict__ ea,
                              const float* __restrict__ ve1, const float* __restrict__ ve2,
                              int* __restrict__ fill, int4* __restrict__ perm) {
    int e = blockIdx.x * blockDim.x + threadIdx.x;
    if (e >= N_EDGES) return;
    const float4* p = (const float4*)(ea + (size_t)e * ED_DIM);
    float4 v0 = p[0], v1 = p[1], v2 = p[2], v3 = p[3];
    float s1 = v0.x*ve1[0] + v0.y*ve1[1] + v0.z*ve1[2] + v0.w*ve1[3]
             + v1.x*ve1[4] + v1.y*ve1[5] + v1.z*ve1[6] + v1.w*ve1[7]
             + v2.x*ve1[8] + v2.y*ve1[9] + v2.z*ve1[10] + v2.w*ve1[11]
             + v3.x*ve1[12] + v3.y*ve1[13] + v3.z*ve1[14] + v3.w*ve1[15];
    float s2 = v0.x*ve2[0] + v0.y*ve2[1] + v0.z*ve2[2] + v0.w*ve2[3]
             + v1.x*ve2[4] + v1.y*ve2[5] + v1.z*ve2[6] + v1.w*ve2[7]
             + v2.x*ve2[8] + v2.y*ve2[9] + v2.z*ve2[10] + v2.w*ve2[11]
             + v3.x*ve2[12] + v3.y*ve2[13] + v3.z*ve2[14] + v3.w*ve2[15];
    int pos = atomicAdd(&fill[dst[e]], 1);
    perm[pos] = make_int4(src[e], __float_as_int(s1), __float_as_int(s2), 0);
}

// conv1 GEMM: h[n,0:128] = fp16( x[n,0:86] @ W1 ), K=86 zero-padded to 96.
// 256 thr = 4 waves (2 row-tiles x 2 col-tiles), block tile 64x128, 16x16x32 f16.
#define KP1 104
__global__ __launch_bounds__(256)
void gemm1(const float* __restrict__ in, const float* __restrict__ W,
           _Float16* __restrict__ hout) {
    __shared__ __attribute__((aligned(16))) _Float16 Asm[64 * KP1];
    __shared__ __attribute__((aligned(16))) _Float16 Bsm[128 * KP1];
    int tid = threadIdx.x;
    int n0 = blockIdx.x * 64;

    // A: 64 rows x 86 floats, contiguous span; float2 loads (86 even)
    const float2* in2 = (const float2*)(in + (size_t)n0 * F_IN);
    for (int idx = tid; idx < 64 * (F_IN / 2); idx += 256) {
        int r = idx / (F_IN / 2), k2 = idx - r * (F_IN / 2);
        float2 v = (n0 + r < N_NODES) ? in2[idx] : make_float2(0.f, 0.f);
        Asm[r * KP1 + 2 * k2]     = (_Float16)v.x;
        Asm[r * KP1 + 2 * k2 + 1] = (_Float16)v.y;
    }
    for (int idx = tid; idx < 64 * (96 - F_IN); idx += 256) {
        int r = idx / (96 - F_IN), k = F_IN + idx - r * (96 - F_IN);
        Asm[r * KP1 + k] = (_Float16)0.f;
    }
    // B: W1 [86][128] floats; float4 loads, transposed store
    const float4* W4 = (const float4*)W;
    for (int idx = tid; idx < F_IN * 32; idx += 256) {
        float4 v = W4[idx];
        int k = idx >> 5, n = (idx & 31) * 4;
        Bsm[(n + 0) * KP1 + k] = (_Float16)v.x;
        Bsm[(n + 1) * KP1 + k] = (_Float16)v.y;
        Bsm[(n + 2) * KP1 + k] = (_Float16)v.z;
        Bsm[(n + 3) * KP1 + k] = (_Float16)v.w;
    }
    for (int idx = tid; idx < 128 * (96 - F_IN); idx += 256) {
        int n = idx / (96 - F_IN), k = F_IN + idx - n * (96 - F_IN);
        Bsm[n * KP1 + k] = (_Float16)0.f;
    }
    __syncthreads();

    int wave = tid >> 6, lane = tid & 63;
    int wm = (wave & 1) * 32, wn = (wave >> 1) * 64;
    int m16 = lane & 15, quad = lane >> 4;

    f4v acc[2][4];
#pragma unroll
    for (int t = 0; t < 2; ++t)
#pragma unroll
        for (int c = 0; c < 4; ++c) acc[t][c] = (f4v){0.f, 0.f, 0.f, 0.f};

#pragma unroll
    for (int kk = 0; kk < 96 / 32; ++kk) {
        int koff = kk * 32 + quad * 8;
        half8 a0 = *(const half8*)&Asm[(wm + m16) * KP1 + koff];
        half8 a1 = *(const half8*)&Asm[(wm + 16 + m16) * KP1 + koff];
#pragma unroll
        for (int c = 0; c < 4; ++c) {
            half8 b = *(const half8*)&Bsm[(wn + c * 16 + m16) * KP1 + koff];
            acc[0][c] = __builtin_amdgcn_mfma_f32_16x16x32_f16(a0, b, acc[0][c], 0, 0, 0);
            acc[1][c] = __builtin_amdgcn_mfma_f32_16x16x32_f16(a1, b, acc[1][c], 0, 0, 0);
        }
    }
#pragma unroll
    for (int t = 0; t < 2; ++t)
#pragma unroll
        for (int c = 0; c < 4; ++c)
#pragma unroll
            for (int r = 0; r < 4; ++r) {
                int row = n0 + wm + t * 16 + quad * 4 + r;
                if (row < N_NODES)
                    hout[(size_t)row * H_DIM + wn + c * 16 + m16] = (_Float16)acc[t][c][r];
            }
}

// conv2 GEMM: h[n,0:128] = fp16( A2[n,0:128] @ W2 ), fp16 input, K=128.
#define KP2 136
__global__ __launch_bounds__(256)
void gemm2(const _Float16* __restrict__ in, const float* __restrict__ W,
           _Float16* __restrict__ hout) {
    __shared__ __attribute__((aligned(16))) _Float16 Asm[64 * KP2];
    __shared__ __attribute__((aligned(16))) _Float16 Bsm[128 * KP2];
    int tid = threadIdx.x;
    int n0 = blockIdx.x * 64;

    const half8* in8 = (const half8*)(in + (size_t)n0 * H_DIM);
    for (int idx = tid; idx < 64 * 16; idx += 256) {
        int r = idx >> 4, k8 = idx & 15;
        half8 v = (n0 + r < N_NODES) ? in8[idx]
                                     : (half8){0, 0, 0, 0, 0, 0, 0, 0};
        *(half8*)&Asm[r * KP2 + k8 * 8] = v;
    }
    const float4* W4 = (const float4*)W;
    for (int idx = tid; idx < 128 * 32; idx += 256) {
        float4 v = W4[idx];
        int k = idx >> 5, n = (idx & 31) * 4;
        Bsm[(n + 0) * KP2 + k] = (_Float16)v.x;
        Bsm[(n + 1) * KP2 + k] = (_Float16)v.y;
        Bsm[(n + 2) * KP2 + k] = (_Float16)v.z;
        Bsm[(n + 3) * KP2 + k] = (_Float16)v.w;
    }
    __syncthreads();

    int wave = tid >> 6, lane = tid & 63;
    int wm = (wave & 1) * 32, wn = (wave >> 1) * 64;
    int m16 = lane & 15, quad = lane >> 4;

    f4v acc[2][4];
#pragma unroll
    for (int t = 0; t < 2; ++t)
#pragma unroll
        for (int c = 0; c < 4; ++c) acc[t][c] = (f4v){0.f, 0.f, 0.f, 0.f};

#pragma unroll
    for (int kk = 0; kk < 128 / 32; ++kk) {
        int koff = kk * 32 + quad * 8;
        half8 a0 = *(const half8*)&Asm[(wm + m16) * KP2 + koff];
        half8 a1 = *(const half8*)&Asm[(wm + 16 + m16) * KP2 + koff];
#pragma unroll
        for (int c = 0; c < 4; ++c) {
            half8 b = *(const half8*)&Bsm[(wn + c * 16 + m16) * KP2 + koff];
            acc[0][c] = __builtin_amdgcn_mfma_f32_16x16x32_f16(a0, b, acc[0][c], 0, 0, 0);
            acc[1][c] = __builtin_amdgcn_mfma_f32_16x16x32_f16(a1, b, acc[1][c], 0, 0, 0);
        }
    }
#pragma unroll
    for (int t = 0; t < 2; ++t)
#pragma unroll
        for (int c = 0; c < 4; ++c)
#pragma unroll
            for (int r = 0; r < 4; ++r) {
                int row = n0 + wm + t * 16 + quad * 4 + r;
                if (row < N_NODES)
                    hout[(size_t)row * H_DIM + wn + c * 16 + m16] = (_Float16)acc[t][c][r];
            }
}

// hs[n]=h[n,:].a_s ; hd[n]=h[n,:].a_d — one wave/node
__global__ void node_dots(const _Float16* __restrict__ h,
                          const float* __restrict__ a_s, const float* __restrict__ a_d,
                          float* __restrict__ hs, float* __restrict__ hd) {
    int n = blockIdx.x * 4 + (threadIdx.x >> 6);
    int l = threadIdx.x & 63;
    if (n >= N_NODES) return;
    h2v v = *(const h2v*)&h[(size_t)n * H_DIM + 2 * l];
    float2 a = ((const float2*)a_s)[l];
    float2 b = ((const float2*)a_d)[l];
    float f0 = (float)v.x, f1 = (float)v.y;
    float ss = f0 * a.x + f1 * a.y;
    float sd = f0 * b.x + f1 * b.y;
    for (int o = 32; o > 0; o >>= 1) {
        ss += __shfl_down(ss, o);
        sd += __shfl_down(sd, o);
    }
    if (l == 0) { hs[n] = ss; hd[n] = sd; }
}

// One wave per dst node, single-pass softmax (|alpha| small; exp w/o max-sub).
// 4 edges per inner iteration: quad q handles edge j*4+q, lane (q,m) loads
// 16 B = dims [8m, 8m+8) of h[src]. Cross-quad reduce at the end.
template<int DOT>
__global__ void gat_node(const int* __restrict__ row_ptr, const int4* __restrict__ perm,
                         const float* __restrict__ hs, const float* __restrict__ hd,
                         const _Float16* __restrict__ h, const float* __restrict__ bias,
                         _Float16* __restrict__ out) {
    int n = blockIdx.x * 4 + (threadIdx.x >> 6);
    int lane = threadIdx.x & 63;
    if (n >= N_NODES) return;
    int q = lane >> 4, m = lane & 15;
    int r0 = row_ptr[n], r1 = row_ptr[n + 1];
    float hdn = hd[n];

    float acc[8];
#pragma unroll
    for (int k = 0; k < 8; ++k) acc[k] = 0.f;
    float denl = 0.f;

    for (int c = r0; c < r1; c += 64) {
        int i = c + lane;
        float w = 0.f;
        int s = 0;
        if (i < r1) {
            int4 p = perm[i];
            s = p.x;
            float dotv = __int_as_float(DOT == 1 ? p.y : p.z);
            float t = hs[s] + hdn + dotv;
            t = (t > 0.f) ? t : NEG_SLOPE * t;
            w = expf(t);
        }
        denl += w;
        int lim = min(64, r1 - c);
        int njj = (lim + 3) >> 2;
        for (int jj = 0; jj < njj; ++jj) {
            int j = (jj << 2) + q;
            float wj = __shfl(w, j);   // w==0 for j>=lim -> contributes nothing
            int sj = __shfl(s, j);
            half8 v = *(const half8*)&h[(size_t)sj * H_DIM + m * 8];
#pragma unroll
            for (int k = 0; k < 8; ++k) acc[k] += wj * (float)v[k];
        }
    }
    // cross-quad reduction: lanes m, m+16, m+32, m+48 hold same dims
#pragma unroll
    for (int k = 0; k < 8; ++k) {
        acc[k] += __shfl_xor(acc[k], 16);
        acc[k] += __shfl_xor(acc[k], 32);
    }
    float den = denl;
#pragma unroll
    for (int o = 32; o > 0; o >>= 1) den += __shfl_xor(den, o);
    float inv = 1.f / fmaxf(den, 1e-16f);

    if (q == 0) {  // lanes 0..15 write dims [8m, 8m+8)
        float4 b0 = ((const float4*)bias)[2 * m];
        float4 b1 = ((const float4*)bias)[2 * m + 1];
        half8 ov;
        ov[0] = (_Float16)fmaxf(acc[0] * inv + b0.x, 0.f);
        ov[1] = (_Float16)fmaxf(acc[1] * inv + b0.y, 0.f);
        ov[2] = (_Float16)fmaxf(acc[2] * inv + b0.z, 0.f);
        ov[3] = (_Float16)fmaxf(acc[3] * inv + b0.w, 0.f);
        ov[4] = (_Float16)fmaxf(acc[4] * inv + b1.x, 0.f);
        ov[5] = (_Float16)fmaxf(acc[5] * inv + b1.y, 0.f);
        ov[6] = (_Float16)fmaxf(acc[6] * inv + b1.z, 0.f);
        ov[7] = (_Float16)fmaxf(acc[7] * inv + b1.w, 0.f);
        *(half8*)&out[(size_t)n * H_DIM + m * 8] = ov;
    }
}

// pooled[g,t] = max over nodes of P[n,t]; P>=0, pooled pre-zeroed
__global__ void pool_max(const _Float16* __restrict__ P,
                         const int* __restrict__ batch, float* __restrict__ pooled) {
    int t = threadIdx.x;  // 128
    int n0 = blockIdx.x * 64;
    int n1 = min(n0 + 64, N_NODES);
    if (n0 >= N_NODES) return;
    int cur = batch[n0];
    float acc = 0.f;
    for (int n = n0; n < n1; ++n) {
        int g = batch[n];
        if (g != cur) {
            atomicMaxFloat(&pooled[cur * H_DIM + t], acc);
            acc = 0.f;
            cur = g;
        }
        acc = fmaxf(acc, (float)P[(size_t)n * H_DIM + t]);
    }
    atomicMaxFloat(&pooled[cur * H_DIM + t], acc);
}

__global__ void final_logits(const float* __restrict__ pooled, const float* __restrict__ Wl,
                             const float* __restrict__ bl, float* __restrict__ outp) {
    int g = threadIdx.x;  // 64
    if (g >= G_GRAPHS) return;
    float lg[C_CLS];
#pragma unroll
    for (int c = 0; c < C_CLS; ++c) lg[c] = bl[c];
    for (int k = 0; k < H_DIM; ++k) {
        float v = pooled[g * H_DIM + k];
#pragma unroll
        for (int c = 0; c < C_CLS; ++c) lg[c] += v * Wl[k * C_CLS + c];
    }
    float mx = lg[0];
#pragma unroll
    for (int c = 1; c < C_CLS; ++c) mx = fmaxf(mx, lg[c]);
    float se = 0.f;
#pragma unroll
    for (int c = 0; c < C_CLS; ++c) se += expf(lg[c] - mx);
    float lse = logf(se);
#pragma unroll
    for (int c = 0; c < C_CLS; ++c) outp[g * C_CLS + c] = lg[c] - mx - lse;
}

extern "C" void kernel_launch(void* const* d_in, const int* in_sizes, int n_in,
                              void* d_out, int out_size, void* d_ws, size_t ws_size,
                              hipStream_t stream) {
    const float* x     = (const float*)d_in[0];
    const int*   eidx  = (const int*)d_in[1];
    const float* ea    = (const float*)d_in[2];
    const int*   batch = (const int*)d_in[3];
    const float* W1  = (const float*)d_in[4];
    const float* We1 = (const float*)d_in[5];
    const float* as1 = (const float*)d_in[6];
    const float* ad1 = (const float*)d_in[7];
    const float* ae1 = (const float*)d_in[8];
    const float* b1  = (const float*)d_in[9];
    const float* W2  = (const float*)d_in[10];
    const float* We2 = (const float*)d_in[11];
    const float* as2 = (const float*)d_in[12];
    const float* ad2 = (const float*)d_in[13];
    const float* ae2 = (const float*)d_in[14];
    const float* b2  = (const float*)d_in[15];
    const float* Wl  = (const float*)d_in[16];
    const float* bl  = (const float*)d_in[17];
    float* outp = (float*)d_out;

    const int* src = eidx;
    const int* dst = eidx + N_EDGES;

    char* wsb = (char*)d_ws;
    size_t off = 0;
    auto alloc = [&](size_t bytes) { char* p = wsb + off; off += (bytes + 255) & ~(size_t)255; return p; };
    _Float16* h    = (_Float16*)alloc((size_t)N_NODES * H_DIM * 2);
    _Float16* A2   = (_Float16*)alloc((size_t)N_NODES * H_DIM * 2);
    _Float16* P    = (_Float16*)alloc((size_t)N_NODES * H_DIM * 2);
    int4*  perm    = (int4*)alloc((size_t)N_EDGES * 16);
    float* hs      = (float*)alloc(N_NODES * 4);
    float* hd      = (float*)alloc(N_NODES * 4);
    int*   row_ptr = (int*)alloc((N_NODES + 1) * 4);
    int*   fill    = (int*)alloc(N_NODES * 4);
    int*   cnt     = (int*)alloc(N_NODES * 4);
    int*   excl    = (int*)alloc(N_NODES * 4);
    int*   bsum    = (int*)alloc(SCAN_BLOCKS * 4);
    float* pooled  = (float*)alloc(G_GRAPHS * H_DIM * 4);
    float* ve1     = (float*)alloc(16 * 4);
    float* ve2     = (float*)alloc(16 * 4);

    const int EB = (N_EDGES + 255) / 256;
    const int NB4 = (N_NODES + 3) / 4;
    const int GB = (N_NODES + 63) / 64;

    // prep (zero cnt + ve + zero pooled) + CSR build
    prep<<<SCAN_BLOCKS + 1, 256, 0, stream>>>(cnt, pooled, We1, ae1, We2, ae2, ve1, ve2);
    hist_dst<<<EB, 256, 0, stream>>>(dst, cnt);
    scan1<<<SCAN_BLOCKS, 256, 0, stream>>>(cnt, excl, bsum);
    scan2<<<1, 256, 0, stream>>>(bsum);
    scan3<<<SCAN_BLOCKS, 256, 0, stream>>>(excl, bsum, row_ptr, fill);
    scatter_edges<<<EB, 256, 0, stream>>>(src, dst, ea, ve1, ve2, fill, perm);

    // ---- conv1 ----
    gemm1<<<GB, 256, 0, stream>>>(x, W1, h);
    node_dots<<<NB4, 256, 0, stream>>>(h, as1, ad1, hs, hd);
    gat_node<1><<<NB4, 256, 0, stream>>>(row_ptr, perm, hs, hd, h, b1, A2);

    // ---- conv2 ----
    gemm2<<<GB, 256, 0, stream>>>(A2, W2, h);
    node_dots<<<NB4, 256, 0, stream>>>(h, as2, ad2, hs, hd);
    gat_node<2><<<NB4, 256, 0, stream>>>(row_ptr, perm, hs, hd, h, b2, P);

    // ---- pool + classifier ----
    pool_max<<<GB, 128, 0, stream>>>(P, batch, pooled);
    final_logits<<<1, 64, 0, stream>>>(pooled, Wl, bl, outp);
}

// Round 5
// 382.057 us; speedup vs baseline: 3.1614x; 1.0124x over previous
//
#include <hip/hip_runtime.h>
#include <math.h>

#define N_NODES 50000
#define N_EDGES 800000
#define F_IN    86
#define H_DIM   128
#define ED_DIM  16
#define C_CLS   18
#define G_GRAPHS 64
#define NEG_SLOPE 0.2f
#define SCAN_BLOCKS ((N_NODES + 255) / 256)   // 196

typedef _Float16 h2v   __attribute__((ext_vector_type(2)));
typedef _Float16 half8 __attribute__((ext_vector_type(8)));
typedef float    f4v   __attribute__((ext_vector_type(4)));

__device__ __forceinline__ void atomicMaxFloat(float* addr, float val) {
    if (val >= 0.0f) atomicMax((int*)addr, __float_as_int(val));
    else             atomicMin((unsigned int*)addr, __float_as_uint(val));
}

// zero cnt (blocks 0..SCAN_BLOCKS-1); ve1/ve2 + zero pooled (block SCAN_BLOCKS)
__global__ void prep(int* __restrict__ cnt, float* __restrict__ pooled,
                     const float* __restrict__ We1, const float* __restrict__ ae1,
                     const float* __restrict__ We2, const float* __restrict__ ae2,
                     float* __restrict__ ve1, float* __restrict__ ve2) {
    int b = blockIdx.x, t = threadIdx.x;
    if (b < SCAN_BLOCKS) {
        int i = b * 256 + t;
        if (i < N_NODES) cnt[i] = 0;
    } else {
        if (t < ED_DIM) {
            float s = 0.f;
            for (int h = 0; h < H_DIM; ++h) s += We1[t * H_DIM + h] * ae1[h];
            ve1[t] = s;
        } else if (t < 2 * ED_DIM) {
            int j = t - ED_DIM;
            float s = 0.f;
            for (int h = 0; h < H_DIM; ++h) s += We2[j * H_DIM + h] * ae2[h];
            ve2[j] = s;
        }
        for (int i = t; i < G_GRAPHS * H_DIM; i += 256) pooled[i] = 0.f;
    }
}

// ---- CSR build ----
__global__ void hist_dst(const int* __restrict__ dst, int* __restrict__ cnt) {
    int e = blockIdx.x * blockDim.x + threadIdx.x;
    if (e < N_EDGES) atomicAdd(&cnt[dst[e]], 1);
}

__global__ void scan1(const int* __restrict__ cnt, int* __restrict__ excl,
                      int* __restrict__ bsum) {
    __shared__ int s[256];
    int tid = threadIdx.x;
    int i = blockIdx.x * 256 + tid;
    int v = (i < N_NODES) ? cnt[i] : 0;
    s[tid] = v;
    __syncthreads();
    for (int o = 1; o < 256; o <<= 1) {
        int t = (tid >= o) ? s[tid - o] : 0;
        __syncthreads();
        s[tid] += t;
        __syncthreads();
    }
    if (i < N_NODES) excl[i] = s[tid] - v;
    if (tid == 255) bsum[blockIdx.x] = s[255];
}

__global__ void scan2(int* __restrict__ bsum) {
    __shared__ int s[256];
    int tid = threadIdx.x;
    int v = (tid < SCAN_BLOCKS) ? bsum[tid] : 0;
    s[tid] = v;
    __syncthreads();
    for (int o = 1; o < 256; o <<= 1) {
        int t = (tid >= o) ? s[tid - o] : 0;
        __syncthreads();
        s[tid] += t;
        __syncthreads();
    }
    if (tid < SCAN_BLOCKS) bsum[tid] = s[tid] - v;
}

__global__ void scan3(const int* __restrict__ excl, const int* __restrict__ bsum,
                      int* __restrict__ row_ptr, int* __restrict__ fill) {
    int i = blockIdx.x * 256 + threadIdx.x;
    if (i < N_NODES) {
        int r = excl[i] + bsum[blockIdx.x];
        row_ptr[i] = r;
        fill[i] = r;
    }
    if (i == 0) row_ptr[N_NODES] = N_EDGES;
}

// scatter edges sorted-by-dst; pack {src, fp16 dot1, fp16 dot2} into 8 B.
// 2 independent edges per thread for atomic/scatter latency ILP.
__global__ void scatter_edges(const int* __restrict__ src, const int* __restrict__ dst,
                              const float* __restrict__ ea,
                              const float* __restrict__ ve1, const float* __restrict__ ve2,
                              int* __restrict__ fill, int2* __restrict__ perm) {
    int t0 = blockIdx.x * 512 + threadIdx.x;
#pragma unroll
    for (int u = 0; u < 2; ++u) {
        int e = t0 + u * 256;
        if (e >= N_EDGES) break;
        const float4* p = (const float4*)(ea + (size_t)e * ED_DIM);
        float4 v0 = p[0], v1 = p[1], v2 = p[2], v3 = p[3];
        float s1 = v0.x*ve1[0] + v0.y*ve1[1] + v0.z*ve1[2] + v0.w*ve1[3]
                 + v1.x*ve1[4] + v1.y*ve1[5] + v1.z*ve1[6] + v1.w*ve1[7]
                 + v2.x*ve1[8] + v2.y*ve1[9] + v2.z*ve1[10] + v2.w*ve1[11]
                 + v3.x*ve1[12] + v3.y*ve1[13] + v3.z*ve1[14] + v3.w*ve1[15];
        float s2 = v0.x*ve2[0] + v0.y*ve2[1] + v0.z*ve2[2] + v0.w*ve2[3]
                 + v1.x*ve2[4] + v1.y*ve2[5] + v1.z*ve2[6] + v1.w*ve2[7]
                 + v2.x*ve2[8] + v2.y*ve2[9] + v2.z*ve2[10] + v2.w*ve2[11]
                 + v3.x*ve2[12] + v3.y*ve2[13] + v3.z*ve2[14] + v3.w*ve2[15];
        h2v dv;
        dv.x = (_Float16)s1;
        dv.y = (_Float16)s2;
        int pos = atomicAdd(&fill[dst[e]], 1);
        perm[pos] = make_int2(src[e], __builtin_bit_cast(int, dv));
    }
}

// conv1 GEMM + fused node dots. h = fp16(x @ W1), K=86 padded to 96.
// 256 thr = 4 waves (2 row x 2 col tiles), block tile 64x128, 16x16x32 f16 MFMA.
#define KP1 104
__global__ __launch_bounds__(256)
void gemm1(const float* __restrict__ in, const float* __restrict__ W,
           const float* __restrict__ a_s, const float* __restrict__ a_d,
           _Float16* __restrict__ hout, float* __restrict__ hs, float* __restrict__ hd) {
    __shared__ __attribute__((aligned(16))) _Float16 Asm[64 * KP1];
    __shared__ __attribute__((aligned(16))) _Float16 Bsm[128 * KP1];
    __shared__ float sdots[64][2][2];   // [row][colhalf][s/d]
    int tid = threadIdx.x;
    int n0 = blockIdx.x * 64;

    const float2* in2 = (const float2*)(in + (size_t)n0 * F_IN);
    for (int idx = tid; idx < 64 * (F_IN / 2); idx += 256) {
        int r = idx / (F_IN / 2), k2 = idx - r * (F_IN / 2);
        float2 v = (n0 + r < N_NODES) ? in2[idx] : make_float2(0.f, 0.f);
        Asm[r * KP1 + 2 * k2]     = (_Float16)v.x;
        Asm[r * KP1 + 2 * k2 + 1] = (_Float16)v.y;
    }
    for (int idx = tid; idx < 64 * (96 - F_IN); idx += 256) {
        int r = idx / (96 - F_IN), k = F_IN + idx - r * (96 - F_IN);
        Asm[r * KP1 + k] = (_Float16)0.f;
    }
    const float4* W4 = (const float4*)W;
    for (int idx = tid; idx < F_IN * 32; idx += 256) {
        float4 v = W4[idx];
        int k = idx >> 5, n = (idx & 31) * 4;
        Bsm[(n + 0) * KP1 + k] = (_Float16)v.x;
        Bsm[(n + 1) * KP1 + k] = (_Float16)v.y;
        Bsm[(n + 2) * KP1 + k] = (_Float16)v.z;
        Bsm[(n + 3) * KP1 + k] = (_Float16)v.w;
    }
    for (int idx = tid; idx < 128 * (96 - F_IN); idx += 256) {
        int n = idx / (96 - F_IN), k = F_IN + idx - n * (96 - F_IN);
        Bsm[n * KP1 + k] = (_Float16)0.f;
    }
    __syncthreads();

    int wave = tid >> 6, lane = tid & 63;
    int wm = (wave & 1) * 32, wn = (wave >> 1) * 64;
    int m16 = lane & 15, quad = lane >> 4;

    f4v acc[2][4];
#pragma unroll
    for (int t = 0; t < 2; ++t)
#pragma unroll
        for (int c = 0; c < 4; ++c) acc[t][c] = (f4v){0.f, 0.f, 0.f, 0.f};

#pragma unroll
    for (int kk = 0; kk < 96 / 32; ++kk) {
        int koff = kk * 32 + quad * 8;
        half8 a0 = *(const half8*)&Asm[(wm + m16) * KP1 + koff];
        half8 a1 = *(const half8*)&Asm[(wm + 16 + m16) * KP1 + koff];
#pragma unroll
        for (int c = 0; c < 4; ++c) {
            half8 b = *(const half8*)&Bsm[(wn + c * 16 + m16) * KP1 + koff];
            acc[0][c] = __builtin_amdgcn_mfma_f32_16x16x32_f16(a0, b, acc[0][c], 0, 0, 0);
            acc[1][c] = __builtin_amdgcn_mfma_f32_16x16x32_f16(a1, b, acc[1][c], 0, 0, 0);
        }
    }

    // epilogue: store h + fused attention dots
    float asv[4], adv[4];
#pragma unroll
    for (int c = 0; c < 4; ++c) {
        asv[c] = a_s[wn + c * 16 + m16];
        adv[c] = a_d[wn + c * 16 + m16];
    }
#pragma unroll
    for (int t = 0; t < 2; ++t)
#pragma unroll
        for (int r = 0; r < 4; ++r) {
            float ps = 0.f, pd = 0.f;
#pragma unroll
            for (int c = 0; c < 4; ++c) {
                float v = acc[t][c][r];
                ps += v * asv[c];
                pd += v * adv[c];
            }
#pragma unroll
            for (int o = 1; o < 16; o <<= 1) {
                ps += __shfl_xor(ps, o);
                pd += __shfl_xor(pd, o);
            }
            if (m16 == 0) {
                int row = wm + t * 16 + quad * 4 + r;
                sdots[row][wn >> 6][0] = ps;
                sdots[row][wn >> 6][1] = pd;
            }
        }
#pragma unroll
    for (int t = 0; t < 2; ++t)
#pragma unroll
        for (int c = 0; c < 4; ++c)
#pragma unroll
            for (int r = 0; r < 4; ++r) {
                int row = n0 + wm + t * 16 + quad * 4 + r;
                if (row < N_NODES)
                    hout[(size_t)row * H_DIM + wn + c * 16 + m16] = (_Float16)acc[t][c][r];
            }
    __syncthreads();
    if (tid < 64) {
        int row = n0 + tid;
        if (row < N_NODES) {
            hs[row] = sdots[tid][0][0] + sdots[tid][1][0];
            hd[row] = sdots[tid][0][1] + sdots[tid][1][1];
        }
    }
}

// conv2 GEMM + fused node dots. fp16 input, K=128.
#define KP2 136
__global__ __launch_bounds__(256)
void gemm2(const _Float16* __restrict__ in, const float* __restrict__ W,
           const float* __restrict__ a_s, const float* __restrict__ a_d,
           _Float16* __restrict__ hout, float* __restrict__ hs, float* __restrict__ hd) {
    __shared__ __attribute__((aligned(16))) _Float16 Asm[64 * KP2];
    __shared__ __attribute__((aligned(16))) _Float16 Bsm[128 * KP2];
    __shared__ float sdots[64][2][2];
    int tid = threadIdx.x;
    int n0 = blockIdx.x * 64;

    const half8* in8 = (const half8*)(in + (size_t)n0 * H_DIM);
    for (int idx = tid; idx < 64 * 16; idx += 256) {
        int r = idx >> 4, k8 = idx & 15;
        half8 v = (n0 + r < N_NODES) ? in8[idx]
                                     : (half8){0, 0, 0, 0, 0, 0, 0, 0};
        *(half8*)&Asm[r * KP2 + k8 * 8] = v;
    }
    const float4* W4 = (const float4*)W;
    for (int idx = tid; idx < 128 * 32; idx += 256) {
        float4 v = W4[idx];
        int k = idx >> 5, n = (idx & 31) * 4;
        Bsm[(n + 0) * KP2 + k] = (_Float16)v.x;
        Bsm[(n + 1) * KP2 + k] = (_Float16)v.y;
        Bsm[(n + 2) * KP2 + k] = (_Float16)v.z;
        Bsm[(n + 3) * KP2 + k] = (_Float16)v.w;
    }
    __syncthreads();

    int wave = tid >> 6, lane = tid & 63;
    int wm = (wave & 1) * 32, wn = (wave >> 1) * 64;
    int m16 = lane & 15, quad = lane >> 4;

    f4v acc[2][4];
#pragma unroll
    for (int t = 0; t < 2; ++t)
#pragma unroll
        for (int c = 0; c < 4; ++c) acc[t][c] = (f4v){0.f, 0.f, 0.f, 0.f};

#pragma unroll
    for (int kk = 0; kk < 128 / 32; ++kk) {
        int koff = kk * 32 + quad * 8;
        half8 a0 = *(const half8*)&Asm[(wm + m16) * KP2 + koff];
        half8 a1 = *(const half8*)&Asm[(wm + 16 + m16) * KP2 + koff];
#pragma unroll
        for (int c = 0; c < 4; ++c) {
            half8 b = *(const half8*)&Bsm[(wn + c * 16 + m16) * KP2 + koff];
            acc[0][c] = __builtin_amdgcn_mfma_f32_16x16x32_f16(a0, b, acc[0][c], 0, 0, 0);
            acc[1][c] = __builtin_amdgcn_mfma_f32_16x16x32_f16(a1, b, acc[1][c], 0, 0, 0);
        }
    }

    float asv[4], adv[4];
#pragma unroll
    for (int c = 0; c < 4; ++c) {
        asv[c] = a_s[wn + c * 16 + m16];
        adv[c] = a_d[wn + c * 16 + m16];
    }
#pragma unroll
    for (int t = 0; t < 2; ++t)
#pragma unroll
        for (int r = 0; r < 4; ++r) {
            float ps = 0.f, pd = 0.f;
#pragma unroll
            for (int c = 0; c < 4; ++c) {
                float v = acc[t][c][r];
                ps += v * asv[c];
                pd += v * adv[c];
            }
#pragma unroll
            for (int o = 1; o < 16; o <<= 1) {
                ps += __shfl_xor(ps, o);
                pd += __shfl_xor(pd, o);
            }
            if (m16 == 0) {
                int row = wm + t * 16 + quad * 4 + r;
                sdots[row][wn >> 6][0] = ps;
                sdots[row][wn >> 6][1] = pd;
            }
        }
#pragma unroll
    for (int t = 0; t < 2; ++t)
#pragma unroll
        for (int c = 0; c < 4; ++c)
#pragma unroll
            for (int r = 0; r < 4; ++r) {
                int row = n0 + wm + t * 16 + quad * 4 + r;
                if (row < N_NODES)
                    hout[(size_t)row * H_DIM + wn + c * 16 + m16] = (_Float16)acc[t][c][r];
            }
    __syncthreads();
    if (tid < 64) {
        int row = n0 + tid;
        if (row < N_NODES) {
            hs[row] = sdots[tid][0][0] + sdots[tid][1][0];
            hd[row] = sdots[tid][0][1] + sdots[tid][1][1];
        }
    }
}

// One wave per dst node, single-pass softmax (|alpha| small; exp w/o max-sub).
// 4 edges per inner iter: quad q -> edge j*4+q; lane (q,m) loads 16 B of h[src].
template<int DOT>
__global__ void gat_node(const int* __restrict__ row_ptr, const int2* __restrict__ perm,
                         const float* __restrict__ hs, const float* __restrict__ hd,
                         const _Float16* __restrict__ h, const float* __restrict__ bias,
                         _Float16* __restrict__ out) {
    int n = blockIdx.x * 4 + (threadIdx.x >> 6);
    int lane = threadIdx.x & 63;
    if (n >= N_NODES) return;
    int q = lane >> 4, m = lane & 15;
    int r0 = row_ptr[n], r1 = row_ptr[n + 1];
    float hdn = hd[n];

    float acc[8];
#pragma unroll
    for (int k = 0; k < 8; ++k) acc[k] = 0.f;
    float denl = 0.f;

    for (int c = r0; c < r1; c += 64) {
        int i = c + lane;
        float w = 0.f;
        int s = 0;
        if (i < r1) {
            int2 p = perm[i];
            s = p.x;
            h2v dv = __builtin_bit_cast(h2v, p.y);
            float dotv = (DOT == 1) ? (float)dv.x : (float)dv.y;
            float t = hs[s] + hdn + dotv;
            t = (t > 0.f) ? t : NEG_SLOPE * t;
            w = expf(t);
        }
        denl += w;
        int lim = min(64, r1 - c);
        int njj = (lim + 3) >> 2;
        for (int jj = 0; jj < njj; ++jj) {
            int j = (jj << 2) + q;
            float wj = __shfl(w, j);   // w==0 for j>=lim -> no contribution
            int sj = __shfl(s, j);
            half8 v = *(const half8*)&h[(size_t)sj * H_DIM + m * 8];
#pragma unroll
            for (int k = 0; k < 8; ++k) acc[k] += wj * (float)v[k];
        }
    }
#pragma unroll
    for (int k = 0; k < 8; ++k) {
        acc[k] += __shfl_xor(acc[k], 16);
        acc[k] += __shfl_xor(acc[k], 32);
    }
    float den = denl;
#pragma unroll
    for (int o = 32; o > 0; o >>= 1) den += __shfl_xor(den, o);
    float inv = 1.f / fmaxf(den, 1e-16f);

    if (q == 0) {
        float4 b0 = ((const float4*)bias)[2 * m];
        float4 b1 = ((const float4*)bias)[2 * m + 1];
        half8 ov;
        ov[0] = (_Float16)fmaxf(acc[0] * inv + b0.x, 0.f);
        ov[1] = (_Float16)fmaxf(acc[1] * inv + b0.y, 0.f);
        ov[2] = (_Float16)fmaxf(acc[2] * inv + b0.z, 0.f);
        ov[3] = (_Float16)fmaxf(acc[3] * inv + b0.w, 0.f);
        ov[4] = (_Float16)fmaxf(acc[4] * inv + b1.x, 0.f);
        ov[5] = (_Float16)fmaxf(acc[5] * inv + b1.y, 0.f);
        ov[6] = (_Float16)fmaxf(acc[6] * inv + b1.z, 0.f);
        ov[7] = (_Float16)fmaxf(acc[7] * inv + b1.w, 0.f);
        *(half8*)&out[(size_t)n * H_DIM + m * 8] = ov;
    }
}

// pooled[g,t] = max over nodes of P[n,t]; P>=0, pooled pre-zeroed
__global__ void pool_max(const _Float16* __restrict__ P,
                         const int* __restrict__ batch, float* __restrict__ pooled) {
    int t = threadIdx.x;  // 128
    int n0 = blockIdx.x * 64;
    int n1 = min(n0 + 64, N_NODES);
    if (n0 >= N_NODES) return;
    int cur = batch[n0];
    float acc = 0.f;
    for (int n = n0; n < n1; ++n) {
        int g = batch[n];
        if (g != cur) {
            atomicMaxFloat(&pooled[cur * H_DIM + t], acc);
            acc = 0.f;
            cur = g;
        }
        acc = fmaxf(acc, (float)P[(size_t)n * H_DIM + t]);
    }
    atomicMaxFloat(&pooled[cur * H_DIM + t], acc);
}

__global__ void final_logits(const float* __restrict__ pooled, const float* __restrict__ Wl,
                             const float* __restrict__ bl, float* __restrict__ outp) {
    int g = threadIdx.x;  // 64
    if (g >= G_GRAPHS) return;
    float lg[C_CLS];
#pragma unroll
    for (int c = 0; c < C_CLS; ++c) lg[c] = bl[c];
    for (int k = 0; k < H_DIM; ++k) {
        float v = pooled[g * H_DIM + k];
#pragma unroll
        for (int c = 0; c < C_CLS; ++c) lg[c] += v * Wl[k * C_CLS + c];
    }
    float mx = lg[0];
#pragma unroll
    for (int c = 1; c < C_CLS; ++c) mx = fmaxf(mx, lg[c]);
    float se = 0.f;
#pragma unroll
    for (int c = 0; c < C_CLS; ++c) se += expf(lg[c] - mx);
    float lse = logf(se);
#pragma unroll
    for (int c = 0; c < C_CLS; ++c) outp[g * C_CLS + c] = lg[c] - mx - lse;
}

extern "C" void kernel_launch(void* const* d_in, const int* in_sizes, int n_in,
                              void* d_out, int out_size, void* d_ws, size_t ws_size,
                              hipStream_t stream) {
    const float* x     = (const float*)d_in[0];
    const int*   eidx  = (const int*)d_in[1];
    const float* ea    = (const float*)d_in[2];
    const int*   batch = (const int*)d_in[3];
    const float* W1  = (const float*)d_in[4];
    const float* We1 = (const float*)d_in[5];
    const float* as1 = (const float*)d_in[6];
    const float* ad1 = (const float*)d_in[7];
    const float* ae1 = (const float*)d_in[8];
    const float* b1  = (const float*)d_in[9];
    const float* W2  = (const float*)d_in[10];
    const float* We2 = (const float*)d_in[11];
    const float* as2 = (const float*)d_in[12];
    const float* ad2 = (const float*)d_in[13];
    const float* ae2 = (const float*)d_in[14];
    const float* b2  = (const float*)d_in[15];
    const float* Wl  = (const float*)d_in[16];
    const float* bl  = (const float*)d_in[17];
    float* outp = (float*)d_out;

    const int* src = eidx;
    const int* dst = eidx + N_EDGES;

    char* wsb = (char*)d_ws;
    size_t off = 0;
    auto alloc = [&](size_t bytes) { char* p = wsb + off; off += (bytes + 255) & ~(size_t)255; return p; };
    _Float16* h    = (_Float16*)alloc((size_t)N_NODES * H_DIM * 2);
    _Float16* A2   = (_Float16*)alloc((size_t)N_NODES * H_DIM * 2);
    _Float16* P    = (_Float16*)alloc((size_t)N_NODES * H_DIM * 2);
    int2*  perm    = (int2*)alloc((size_t)N_EDGES * 8);
    float* hs      = (float*)alloc(N_NODES * 4);
    float* hd      = (float*)alloc(N_NODES * 4);
    int*   row_ptr = (int*)alloc((N_NODES + 1) * 4);
    int*   fill    = (int*)alloc(N_NODES * 4);
    int*   cnt     = (int*)alloc(N_NODES * 4);
    int*   excl    = (int*)alloc(N_NODES * 4);
    int*   bsum    = (int*)alloc(SCAN_BLOCKS * 4);
    float* pooled  = (float*)alloc(G_GRAPHS * H_DIM * 4);
    float* ve1     = (float*)alloc(16 * 4);
    float* ve2     = (float*)alloc(16 * 4);

    const int EB = (N_EDGES + 255) / 256;
    const int NB4 = (N_NODES + 3) / 4;
    const int GB = (N_NODES + 63) / 64;

    // prep + CSR build
    prep<<<SCAN_BLOCKS + 1, 256, 0, stream>>>(cnt, pooled, We1, ae1, We2, ae2, ve1, ve2);
    hist_dst<<<EB, 256, 0, stream>>>(dst, cnt);
    scan1<<<SCAN_BLOCKS, 256, 0, stream>>>(cnt, excl, bsum);
    scan2<<<1, 256, 0, stream>>>(bsum);
    scan3<<<SCAN_BLOCKS, 256, 0, stream>>>(excl, bsum, row_ptr, fill);
    scatter_edges<<<(N_EDGES + 511) / 512, 256, 0, stream>>>(src, dst, ea, ve1, ve2, fill, perm);

    // ---- conv1 ----
    gemm1<<<GB, 256, 0, stream>>>(x, W1, as1, ad1, h, hs, hd);
    gat_node<1><<<NB4, 256, 0, stream>>>(row_ptr, perm, hs, hd, h, b1, A2);

    // ---- conv2 ----
    gemm2<<<GB, 256, 0, stream>>>(A2, W2, as2, ad2, h, hs, hd);
    gat_node<2><<<NB4, 256, 0, stream>>>(row_ptr, perm, hs, hd, h, b2, P);

    // ---- pool + classifier ----
    pool_max<<<GB, 128, 0, stream>>>(P, batch, pooled);
    final_logits<<<1, 64, 0, stream>>>(pooled, Wl, bl, outp);
}